// Round 28
// baseline (238.094 us; speedup 1.0000x reference)
//
#include <hip/hip_runtime.h>

#define BATCH 4096
#define SEQ   200
#define HID   128
#define ROWS  16
#define NTH   512
#define FB    (4 * 64 * 8)   // f16 elements per fragment buffer

typedef _Float16 f16;
typedef f16 f16x4 __attribute__((ext_vector_type(4)));
typedef f16 f16x8 __attribute__((ext_vector_type(8)));
typedef float f32x4 __attribute__((ext_vector_type(4)));

#define MFMA(a, b, c) __builtin_amdgcn_mfma_f32_16x16x32_f16((a), (b), (c), 0, 0, 0)

__device__ __forceinline__ float fast_exp2(float x) {
#if defined(__has_builtin) && __has_builtin(__builtin_amdgcn_exp2f)
    return __builtin_amdgcn_exp2f(x);
#else
    float r; asm volatile("v_exp_f32 %0, %1\n\ts_nop 0" : "=v"(r) : "v"(x)); return r;
#endif
}
__device__ __forceinline__ float fast_rcp(float x) {
#if defined(__has_builtin) && __has_builtin(__builtin_amdgcn_rcpf)
    return __builtin_amdgcn_rcpf(x);
#else
    float r; asm volatile("v_rcp_f32 %0, %1\n\ts_nop 0" : "=v"(r) : "v"(x)); return r;
#endif
}
#define LOG2E  1.442695041f
#define LOG2E2 2.885390082f

// Persistent GRU, v19 = v17 with ALL LDS addressing compile-time constant.
// Round 27 falsified latency-hiding (occupancy 2x -> dur +10%); v17's
// VALUBusy 49% implies ~290 VALU issues/wave-step — ~2x the gates+staging
// need. The excess is runtime address arithmetic (triple-buffer rotation,
// cur/nxt muls, tok_sh roundtrip). Fixes:
//  1) x 2-ahead staging needs only a DOUBLE buffer (read x(s+1) from
//     buf (s+1)&1, write x(s+2) to buf s&1 — disjoint, barrier-separated).
//  2) Unroll the scan by 2: every xb/hb buffer index is a literal ->
//     ds offsets fold into instruction immediates.
//  3) tok_sh (LDS) -> per-lane register token pipes (gate 3-deep,
//     stage 2-deep, clamped at tail; staged garbage never read).
// Else identical to v17: transposed dataflow, weights in regs as A-operand
// (AGPR-backed), x-proj pipelined 1 step ahead as h-chain C-init,
// conflict-free 8B staging, h-scatter 1 b64, out 1 dwordx4, 1 barrier/step.
__global__ __attribute__((amdgpu_flat_work_group_size(NTH, NTH)))
void gru_mfma(const int* __restrict__ inputs,
              const float* __restrict__ emb,
              const float* __restrict__ kernel,
              const float* __restrict__ rec_kernel,
              const float* __restrict__ bias,
              float* __restrict__ out)
{
    __shared__ __align__(16) f16 xb[2][4][64][8];    // x^T frags, dbuf, 8 KB
    __shared__ __align__(16) f16 hb[2][4][64][8];    // h^T frags, dbuf, 8 KB
    __shared__ int ts_sh;

    const int tid  = threadIdx.x;
    const int lane = tid & 63;
    const int j0   = (tid >> 6) * 16;   // wave's hid-column slice
    const int l15  = lane & 15;         // batch index within tile
    const int hi   = lane >> 4;
    const int r0   = hi * 4;            // out_col = j0+r0+i
    const int row0 = blockIdx.x * ROWS;

    // int32-vs-int64 token stride, detected from data (int64 LE: odd words 0)
    if (tid == 0) { int any = 0; for (int i = 1; i < 128; i += 2) any |= inputs[i]; ts_sh = any ? 1 : 2; }

    // --- one-time weight fragments (gate scales folded), A operand ---
    f16x8 Bx[3][4];
    f16x8 Brz[4], Brr[4], Brh[4];
    const float gsc[3] = { -LOG2E, -LOG2E, LOG2E2 };
#pragma unroll
    for (int g = 0; g < 3; ++g)
#pragma unroll
        for (int kt = 0; kt < 4; ++kt) {
            f16x8 t;
#pragma unroll
            for (int e = 0; e < 8; ++e)
                t[e] = (f16)(gsc[g] * kernel[(size_t)(kt * 32 + hi * 8 + e) * 384 + g * HID + j0 + l15]);
            Bx[g][kt] = t;
        }
#pragma unroll
    for (int kt = 0; kt < 4; ++kt) {
        f16x8 tz, tr, th;
#pragma unroll
        for (int e = 0; e < 8; ++e) {
            const size_t krow = (size_t)(kt * 32 + hi * 8 + e) * 384;
            tz[e] = (f16)(-LOG2E  * rec_kernel[krow + j0 + l15]);
            tr[e] = (f16)(-LOG2E  * rec_kernel[krow + HID + j0 + l15]);
            th[e] = (f16)(LOG2E2 * rec_kernel[krow + 2 * HID + j0 + l15]);
        }
        Brz[kt] = tz; Brr[kt] = tr; Brh[kt] = th;
    }

    f32x4 bzv, brv, bxhv, brhv;
#pragma unroll
    for (int i = 0; i < 4; ++i) {
        const int c = j0 + r0 + i;
        bzv[i]  = -LOG2E * (bias[c]       + bias[384 + c]);
        brv[i]  = -LOG2E * (bias[128 + c] + bias[512 + c]);
        bxhv[i] =  LOG2E2 * bias[256 + c];
        brhv[i] =  LOG2E2 * bias[640 + c];
    }

    f32x4 h = {0.f, 0.f, 0.f, 0.f};     // h[batch=l15][j0+r0+i]

    const int hk  = j0 + r0;
    const int hwi = (((hk >> 5) * 64) + (((hk & 31) >> 3) * 16) + l15) * 8 + (hk & 7);

    // stager: each thread owns half a 16B fragment unit
    const int skt   = tid >> 7;
    const int sidx  = tid & 127;
    const int su    = sidx >> 1;
    const int shalf = sidx & 1;
    const int sb    = su & 15;
    const int shid  = skt * 32 + (su >> 4) * 8 + shalf * 4;
    const int sw    = (skt * 64 + su) * 8 + shalf * 4;

    // zero hb[0] (step-0 scatter fully covers hb[1])
    for (int i = tid; i < FB; i += NTH) ((f16*)hb)[i] = (f16)0.f;
    __syncthreads();                    // ts_sh + zero visible
    const int ts = ts_sh;

    // --- token pipelines (registers, no LDS) ---
    const size_t tbS = (size_t)(row0 + sb)  * SEQ;   // stage rows
    const size_t tbG = (size_t)(row0 + l15) * SEQ;   // gate rows
    int gA = inputs[(tbG + 0) * ts];
    int gB = inputs[(tbG + 1) * ts];
    int gC = inputs[(tbG + 2) * ts];
    const int tk0 = inputs[(tbS + 0) * ts];
    const int tk1 = inputs[(tbS + 1) * ts];
    int tok2 = inputs[(tbS + 2) * ts];               // stage token for s+2

    // stage x(0)->xb[0], x(1)->xb[1]
    {
        const float4 v0 = *(const float4*)&emb[(size_t)tk0 * HID + shid];
        const float4 v1 = *(const float4*)&emb[(size_t)tk1 * HID + shid];
        f16x4 a; a[0] = (f16)v0.x; a[1] = (f16)v0.y; a[2] = (f16)v0.z; a[3] = (f16)v0.w;
        f16x4 b; b[0] = (f16)v1.x; b[1] = (f16)v1.y; b[2] = (f16)v1.z; b[3] = (f16)v1.w;
        *(f16x4*)&((f16*)xb)[sw] = a;          // buf 0
        *(f16x4*)&((f16*)xb)[FB + sw] = b;     // buf 1
    }
    __syncthreads();

    // initial x-projections for s=0 from xb[0]
    f32x4 azx = bzv, arx = brv, axc = bxhv;
#pragma unroll
    for (int kt = 0; kt < 4; ++kt) {
        const f16x8 xB = *(const f16x8*)&xb[0][kt][lane][0];
        azx = MFMA(Bx[0][kt], xB, azx);
        arx = MFMA(Bx[1][kt], xB, arx);
        axc = MFMA(Bx[2][kt], xB, axc);
    }

#define GRU_STEP(HRD, HWR, XRD, XWR, SOFF)                                     \
    {                                                                          \
        const int sl = (ss + (SOFF) < SEQ) ? ss + (SOFF) : SEQ - 1;            \
        const float4 pv = *(const float4*)&emb[(size_t)tok2 * HID + shid];     \
        const int tokN = inputs[(tbS + sl) * ts];                              \
        const int gN   = inputs[(tbG + sl) * ts];                              \
        f32x4 az = azx, ar = arx, ah = brhv;                                   \
        _Pragma("unroll")                                                      \
        for (int kt = 0; kt < 4; ++kt) {                                       \
            const f16x8 hB = *(const f16x8*)&hb[HRD][kt][lane][0];             \
            az = MFMA(Brz[kt], hB, az);                                        \
            ar = MFMA(Brr[kt], hB, ar);                                        \
            ah = MFMA(Brh[kt], hB, ah);                                        \
        }                                                                      \
        f16x4 hv;                                                              \
        _Pragma("unroll")                                                      \
        for (int i = 0; i < 4; ++i) {                                          \
            const float z  = fast_rcp(1.f + fast_exp2(az[i]));                 \
            const float rg = fast_rcp(1.f + fast_exp2(ar[i]));                 \
            const float u  = axc[i] + rg * ah[i];                              \
            const float hh = 1.f - 2.f * fast_rcp(1.f + fast_exp2(u));         \
            const float hn = hh + z * (h[i] - hh);                             \
            h[i] = (gA != 0) ? hn : h[i];                                      \
            hv[i] = (f16)h[i];                                                 \
        }                                                                      \
        *(f16x4*)&((f16*)hb)[(HWR) * FB + hwi] = hv;                           \
        /* barrier-shadow: next step's x-projections + staging */              \
        azx = bzv; arx = brv; axc = bxhv;                                      \
        _Pragma("unroll")                                                      \
        for (int kt = 0; kt < 4; ++kt) {                                       \
            const f16x8 xB = *(const f16x8*)&xb[XRD][kt][lane][0];             \
            azx = MFMA(Bx[0][kt], xB, azx);                                    \
            arx = MFMA(Bx[1][kt], xB, arx);                                    \
            axc = MFMA(Bx[2][kt], xB, axc);                                    \
        }                                                                      \
        {                                                                      \
            f16x4 xv; xv[0] = (f16)pv.x; xv[1] = (f16)pv.y;                    \
            xv[2] = (f16)pv.z; xv[3] = (f16)pv.w;                              \
            *(f16x4*)&((f16*)xb)[(XWR) * FB + sw] = xv;                        \
        }                                                                      \
        gA = gB; gB = gC; gC = gN; tok2 = tokN;                                \
        __syncthreads();                                                       \
    }

    for (int ss = 0; ss < SEQ; ss += 2) {
        GRU_STEP(0, 1, 1, 0, 3)   // step s=ss
        GRU_STEP(1, 0, 0, 1, 4)   // step s=ss+1
    }
#undef GRU_STEP

    // out: 4 consecutive hid cols for batch l15 -> one dwordx4
    float4 o; o.x = h[0]; o.y = h[1]; o.z = h[2]; o.w = h[3];
    *(float4*)&out[(size_t)(row0 + l15) * HID + j0 + r0] = o;
}

extern "C" void kernel_launch(void* const* d_in, const int* in_sizes, int n_in,
                              void* d_out, int out_size, void* d_ws, size_t ws_size,
                              hipStream_t stream) {
    const int* inputs      = (const int*)d_in[0];
    const float* emb       = (const float*)d_in[1];
    const float* kernel    = (const float*)d_in[2];
    const float* rec_k     = (const float*)d_in[3];
    const float* bias      = (const float*)d_in[4];
    float* out             = (float*)d_out;
    gru_mfma<<<BATCH / ROWS, NTH, 0, stream>>>(inputs, emb, kernel, rec_k, bias, out);
}

// Round 29
// 166.686 us; speedup vs baseline: 1.4284x; 1.4284x over previous
//
#include <hip/hip_runtime.h>

#define BATCH 4096
#define SEQ   200
#define HID   128
#define ROWS  16
#define NTH   512

typedef _Float16 f16;
typedef f16 f16x4 __attribute__((ext_vector_type(4)));
typedef f16 f16x8 __attribute__((ext_vector_type(8)));
typedef float f32x4 __attribute__((ext_vector_type(4)));

#define MFMA(a, b, c) __builtin_amdgcn_mfma_f32_16x16x32_f16((a), (b), (c), 0, 0, 0)

__device__ __forceinline__ float fast_exp2(float x) {
#if defined(__has_builtin) && __has_builtin(__builtin_amdgcn_exp2f)
    return __builtin_amdgcn_exp2f(x);
#else
    float r; asm volatile("v_exp_f32 %0, %1\n\ts_nop 0" : "=v"(r) : "v"(x)); return r;
#endif
}
__device__ __forceinline__ float fast_rcp(float x) {
#if defined(__has_builtin) && __has_builtin(__builtin_amdgcn_rcpf)
    return __builtin_amdgcn_rcpf(x);
#else
    float r; asm volatile("v_rcp_f32 %0, %1\n\ts_nop 0" : "=v"(r) : "v"(x)); return r;
#endif
}
#define LOG2E  1.442695041f
#define LOG2E2 2.885390082f

// Persistent GRU, v17 (REVERT to round-26 best: 166.8us).
// Round 28's v19 (compile-time LDS addressing + unroll-by-2 + register token
// pipes) regressed 197->278us dispatch with proportional VALUBusy/MfmaUtil
// drops — pure added stall, theory falsified. v17 has now resisted six
// structural perturbations (r21 ILP, r24 stager split, r27 wave
// specialization, r28 const-addressing all regressed; r25/r26 gained 2%).
// Structure: transposed dataflow (weights = A operand in regs/AGPRs, x/h =
// B from LDS frags); x-projection pipelined ONE STEP AHEAD (triple-buffer
// xb, xp computed in barrier shadow, carried as h-chain C-init); conflict-
// free 8B-granular staging (load top / convert+write bottom); h-scatter one
// b64; out one dwordx4; one barrier per step.
__global__ __attribute__((amdgpu_flat_work_group_size(NTH, NTH)))
void gru_mfma(const int* __restrict__ inputs,
              const float* __restrict__ emb,
              const float* __restrict__ kernel,
              const float* __restrict__ rec_kernel,
              const float* __restrict__ bias,
              float* __restrict__ out)
{
    // fragment buffers: f16 idx ((buf*4 + kt)*64 + unit)*8 + e
    __shared__ __align__(16) f16 xb[3][4][64][8];    // x^T frags, TRIPLE buf, 12 KB
    __shared__ __align__(16) f16 hb[2][4][64][8];    // h^T frags, dbuf, 8 KB
    __shared__ int tok_sh[2][ROWS];
    __shared__ int ts_sh;

    const int tid  = threadIdx.x;
    const int lane = tid & 63;
    const int j0   = (tid >> 6) * 16;   // wave's hid-column slice
    const int l15  = lane & 15;         // batch index within tile
    const int hi   = lane >> 4;         // 0..3
    const int r0   = hi * 4;            // D row base -> out_col = j0+r0+i
    const int row0 = blockIdx.x * ROWS;

    // int32-vs-int64 token stride, detected from data (int64 LE: odd words 0)
    if (tid == 0) { int any = 0; for (int i = 1; i < 128; i += 2) any |= inputs[i]; ts_sh = any ? 1 : 2; }

    // --- one-time weight fragments (gate scales folded), used as A operand ---
    f16x8 Bx[3][4];                 // kernel: z,r scaled -LOG2E; h scaled +LOG2E2
    f16x8 Brz[4], Brr[4], Brh[4];   // rec_kernel, same scaling
    const float gsc[3] = { -LOG2E, -LOG2E, LOG2E2 };
#pragma unroll
    for (int g = 0; g < 3; ++g)
#pragma unroll
        for (int kt = 0; kt < 4; ++kt) {
            f16x8 t;
#pragma unroll
            for (int e = 0; e < 8; ++e)
                t[e] = (f16)(gsc[g] * kernel[(size_t)(kt * 32 + hi * 8 + e) * 384 + g * HID + j0 + l15]);
            Bx[g][kt] = t;
        }
#pragma unroll
    for (int kt = 0; kt < 4; ++kt) {
        f16x8 tz, tr, th;
#pragma unroll
        for (int e = 0; e < 8; ++e) {
            const size_t krow = (size_t)(kt * 32 + hi * 8 + e) * 384;
            tz[e] = (f16)(-LOG2E  * rec_kernel[krow + j0 + l15]);
            tr[e] = (f16)(-LOG2E  * rec_kernel[krow + HID + j0 + l15]);
            th[e] = (f16)(LOG2E2 * rec_kernel[krow + 2 * HID + j0 + l15]);
        }
        Brz[kt] = tz; Brr[kt] = tr; Brh[kt] = th;
    }

    // biases for this lane's out_cols j0+r0+i
    f32x4 bzv, brv, bxhv, brhv;
#pragma unroll
    for (int i = 0; i < 4; ++i) {
        const int c = j0 + r0 + i;
        bzv[i]  = -LOG2E * (bias[c]       + bias[384 + c]);
        brv[i]  = -LOG2E * (bias[128 + c] + bias[512 + c]);
        bxhv[i] =  LOG2E2 * bias[256 + c];
        brhv[i] =  LOG2E2 * bias[640 + c];
    }

    f32x4 h = {0.f, 0.f, 0.f, 0.f};     // h[batch=l15][j0+r0+i]

    // h-scatter dest: hid = j0+r0, batch = l15 (one b64 per lane)
    const int hk  = j0 + r0;
    const int hwi = (((hk >> 5) * 64) + (((hk & 31) >> 3) * 16) + l15) * 8 + (hk & 7);

    // stager role: all 512 threads, each owns HALF a 16B fragment unit
    const int skt  = tid >> 7;                 // kt slab 0..3
    const int sidx = tid & 127;
    const int su   = sidx >> 1;                // unit = ug*16 + batch
    const int shalf= sidx & 1;                 // which 8B half
    const int sb   = su & 15;                  // batch row
    const int shid = skt * 32 + (su >> 4) * 8 + shalf * 4;   // first hid (4 wide)
    const int sw   = (skt * 64 + su) * 8 + shalf * 4;        // f16 idx within buf
    const bool twr = (tid < 32) && ((tid & 1) == 0);  // tok_sh writer (sb=tid>>1)

    // --- zero hb[0] (step-0 scatter fully covers hb[1]) ---
    for (int i = tid; i < 4 * 64 * 8; i += NTH) ((f16*)hb)[i] = (f16)0.f;
    __syncthreads();                    // ts_sh + zero done
    const int ts = ts_sh;

    // --- prologue: tokens 0..2; stage x(0)->xb[0], x(1)->xb[1] ---
    const size_t tbase = (size_t)(row0 + sb) * SEQ;
    const int tok0 = inputs[(tbase + 0) * ts];
    int t1 = inputs[(tbase + 1) * ts];   // token(s+1) for gates
    int t2 = inputs[(tbase + 2) * ts];   // token(s+2) for x staging
    if (twr) tok_sh[0][sb] = tok0;
    {
        const float4 v0 = *(const float4*)&emb[(size_t)tok0 * HID + shid];
        const float4 v1 = *(const float4*)&emb[(size_t)t1   * HID + shid];
        f16x4 a; a[0] = (f16)v0.x; a[1] = (f16)v0.y; a[2] = (f16)v0.z; a[3] = (f16)v0.w;
        f16x4 b; b[0] = (f16)v1.x; b[1] = (f16)v1.y; b[2] = (f16)v1.z; b[3] = (f16)v1.w;
        *(f16x4*)&((f16*)xb)[sw] = a;                    // buf 0
        *(f16x4*)&((f16*)xb)[1 * (4 * 64 * 8) + sw] = b; // buf 1
    }
    __syncthreads();

    // initial x-projections for s=0 from xb[0]
    f32x4 azx = bzv, arx = brv, axc = bxhv;
#pragma unroll
    for (int kt = 0; kt < 4; ++kt) {
        const f16x8 xB = *(const f16x8*)&xb[0][kt][lane][0];
        azx = MFMA(Bx[0][kt], xB, azx);
        arx = MFMA(Bx[1][kt], xB, arx);
        axc = MFMA(Bx[2][kt], xB, axc);
    }

    int rd_x = 1, wr_x = 2;
    for (int s = 0; s < SEQ; ++s) {
        const int cur = s & 1, nxt = cur ^ 1;
        const bool pf1 = (s + 1 < SEQ);
        const bool pf2 = (s + 2 < SEQ);
        float4 pv; int t3 = t2;
        if (pf2) {   // issue x(s+2) load at TOP; first use after gates
            pv = *(const float4*)&emb[(size_t)t2 * HID + shid];
            const int s3 = (s + 3 < SEQ) ? (s + 3) : (SEQ - 1);
            t3 = inputs[(tbase + s3) * ts];
        }

        const int tkk = tok_sh[cur][l15];   // this lane's batch token

        // h-chains; C-init = carried x-projections (az,ar) / brh bias (ah)
        f32x4 az = azx, ar = arx, ah = brhv;
#pragma unroll
        for (int kt = 0; kt < 4; ++kt) {
            const f16x8 hB = *(const f16x8*)&hb[cur][kt][lane][0];
            az = MFMA(Brz[kt], hB, az);
            ar = MFMA(Brr[kt], hB, ar);
            ah = MFMA(Brh[kt], hB, ah);
        }

        // gates — lane-local (batch l15, out_cols j0+r0+i)
        f16x4 hv;
#pragma unroll
        for (int i = 0; i < 4; ++i) {
            const float z  = fast_rcp(1.f + fast_exp2(az[i]));
            const float rg = fast_rcp(1.f + fast_exp2(ar[i]));
            const float u  = axc[i] + rg * ah[i];             // 2*log2e-scaled
            const float hh = 1.f - 2.f * fast_rcp(1.f + fast_exp2(u));
            const float hn = hh + z * (h[i] - hh);
            h[i] = (tkk != 0) ? hn : h[i];
            hv[i] = (f16)h[i];
        }

        // scatter h^T frag (critical path ends here)
        *(f16x4*)&((f16*)hb)[nxt * (4 * 64 * 8) + hwi] = hv;

        // ---- barrier-shadow work: next step's x-projections + staging ----
        if (pf1) {
            azx = bzv; arx = brv; axc = bxhv;
#pragma unroll
            for (int kt = 0; kt < 4; ++kt) {
                const f16x8 xB = *(const f16x8*)&xb[rd_x][kt][lane][0];
                azx = MFMA(Bx[0][kt], xB, azx);
                arx = MFMA(Bx[1][kt], xB, arx);
                axc = MFMA(Bx[2][kt], xB, axc);
            }
            if (twr) tok_sh[nxt][sb] = t1;
        }
        if (pf2) {   // convert prefetched x(s+2) + write (conflict-free slab)
            f16x4 xv; xv[0] = (f16)pv.x; xv[1] = (f16)pv.y; xv[2] = (f16)pv.z; xv[3] = (f16)pv.w;
            *(f16x4*)&((f16*)xb)[wr_x * (4 * 64 * 8) + sw] = xv;
        }
        t1 = t2; t2 = t3;
        rd_x = (rd_x == 2) ? 0 : rd_x + 1;
        wr_x = (wr_x == 2) ? 0 : wr_x + 1;
        __syncthreads();   // hb[nxt]/xb/tok ready; sole barrier per step
    }

    // out: 4 consecutive hid cols for batch l15 -> one dwordx4
    float4 o; o.x = h[0]; o.y = h[1]; o.z = h[2]; o.w = h[3];
    *(float4*)&out[(size_t)(row0 + l15) * HID + j0 + r0] = o;
}

extern "C" void kernel_launch(void* const* d_in, const int* in_sizes, int n_in,
                              void* d_out, int out_size, void* d_ws, size_t ws_size,
                              hipStream_t stream) {
    const int* inputs      = (const int*)d_in[0];
    const float* emb       = (const float*)d_in[1];
    const float* kernel    = (const float*)d_in[2];
    const float* rec_k     = (const float*)d_in[3];
    const float* bias      = (const float*)d_in[4];
    float* out             = (float*)d_out;
    gru_mfma<<<BATCH / ROWS, NTH, 0, stream>>>(inputs, emb, kernel, rec_k, bias, out);
}